// Round 7
// baseline (8761.909 us; speedup 1.0000x reference)
//
#include <hip/hip_runtime.h>
#include <math.h>

#define B_ 64
#define T_ 100
#define S_ 32
#define L_ 128
#define R_ 16
#define H_ 256

__device__ __forceinline__ float dot4(float4 a, float4 b) {
  return a.x*b.x + a.y*b.y + a.z*b.z + a.w*b.w;
}
__device__ __forceinline__ void wave_fence() {
  asm volatile("s_waitcnt lgkmcnt(0)" ::: "memory");
  __builtin_amdgcn_wave_barrier();
}

// ---- 16x16 cholesky (row-per-lane, shfl) + explicit G = inv(L) ---- (verified r3/r4)
__device__ __forceinline__ void chol16_inv(int lane, float (*C2)[17], float (*G)[17], float* rd) {
  float row[16];
  #pragma unroll
  for (int c = 0; c < 16; ++c) row[c] = (lane < 16) ? C2[lane][c] : 0.0f;
  float rdg = 0.0f;
  #pragma unroll
  for (int j = 0; j < 16; ++j) {
    float dsq = __shfl(row[j], j);
    float d = sqrtf(dsq);
    float inv = 1.0f / d;
    float cij = row[j] * inv;
    if (lane == j) { cij = d; rdg = inv; }
    row[j] = cij;
    float upd = (lane > j) ? (cij * inv) : 0.0f;
    #pragma unroll
    for (int c = j + 1; c < 16; ++c) {
      float cjc = __shfl(row[c], j);
      row[c] -= upd * cjc;
    }
  }
  if (lane < 16) {
    #pragma unroll
    for (int c = 0; c < 16; ++c) C2[lane][c] = row[c];
    rd[lane] = rdg;
  }
  wave_fence();
  if (lane < 16) {
    const int c = lane;
    float g[16];
    #pragma unroll
    for (int i = 0; i < 16; ++i) {
      float a = (i == c) ? 1.0f : 0.0f;
      #pragma unroll
      for (int j2 = 0; j2 < 16; ++j2) if (j2 < i) a -= C2[i][j2] * g[j2];
      g[i] = a * rd[i];
    }
    #pragma unroll
    for (int i = 0; i < 16; ++i) G[i][c] = (i >= c) ? g[i] : 0.0f;
  }
  wave_fence();
}

// ---- 32x32 cholesky + full solve (L L^T) x = t1 -> xb (verified r3/r4) ----
__device__ __forceinline__ void chol32_fs(int lane, float (*C)[33],
                                          const float* t1, float* xb) {
  float row[32];
  #pragma unroll
  for (int c = 0; c < 32; ++c) row[c] = (lane < 32) ? C[lane][c] : 0.0f;
  float rdg = 0.0f;
  #pragma unroll
  for (int j = 0; j < 32; ++j) {
    float dsq = __shfl(row[j], j);
    float d = sqrtf(dsq);
    float inv = 1.0f / d;
    float cij = row[j] * inv;
    if (lane == j) { cij = d; rdg = inv; }
    row[j] = cij;
    float upd = (lane > j) ? (cij * inv) : 0.0f;
    #pragma unroll
    for (int c = j + 1; c < 32; ++c) {
      float cjc = __shfl(row[c], j);
      row[c] -= upd * cjc;
    }
  }
  float acc = (lane < 32) ? t1[lane] : 0.0f;
  #pragma unroll
  for (int j = 0; j < 32; ++j) {
    float xj = __shfl(acc, j) * __shfl(rdg, j);
    if (lane == j) acc = xj;
    else if (lane > j) acc -= row[j] * xj;
  }
  if (lane < 32) {
    #pragma unroll
    for (int c = 0; c < 32; ++c) C[lane][c] = row[c];
  }
  wave_fence();
  float colT[32];
  #pragma unroll
  for (int j = 0; j < 32; ++j) colT[j] = (lane < 32) ? C[j][lane] : 0.0f;
  float acc2 = acc;
  float xi = 0.0f;
  #pragma unroll
  for (int j = 31; j >= 0; --j) {
    float xj = __shfl(acc2, j) * __shfl(rdg, j);
    if (lane == j) xi = xj;
    if (lane < j) acc2 -= colT[j] * xj;
  }
  if (lane < 32) xb[lane] = xi;
  wave_fence();
}

__global__ __launch_bounds__(1024) void filter_kernel(
    const float* __restrict__ kg,   // (B,T,L)
    const float* __restrict__ Kg,   // (B,T,L,R)
    const float* __restrict__ m0g,  // (L)
    const float* __restrict__ Ppg,  // (L)
    const float* __restrict__ Qg,   // (L)
    const float* __restrict__ wp0,  // (S,B,L)
    const float* __restrict__ wf0,  // (S,B,R)
    const float* __restrict__ wp1s, // (T-1,S,B,S)
    const float* __restrict__ wp2s, // (T-1,S,B,L)
    const float* __restrict__ wfs,  // (T-1,S,B,R)
    const float* __restrict__ W1,   // (L,H) row-major
    const float* __restrict__ W2,   // (H,L) row-major
    float* __restrict__ out)        // (T,S,B,L)
{
  const int b = blockIdx.x;
  const int tid = threadIdx.x;
  const int lane_l = tid & 31;     // 0..31 within half-wave
  const int sp = tid >> 5;         // particle owned in GEMM/store mapping

  __shared__ float Ab[S_][132];    // McQ = Mc * iQ
  __shared__ float Mc[S_][132];    // m_theta -> centered Mc
  __shared__ float zp[S_][132];    // z_p_c, then (zp - K x)
  __shared__ float KtT[R_][132];   // K_t^T [r][l]
  __shared__ float w1b[S_][36];
  __shared__ float wfb[S_][20];
  __shared__ float C32m[32][33];
  __shared__ float C2m[16][17];
  __shared__ float Gm[16][17];
  __shared__ float KMm[16][36];
  __shared__ float v1b[S_][20];
  __shared__ float yb[S_][20];     // step-0 only
  __shared__ float xvb[S_][20];    // step-0 only
  __shared__ float red[32][17];
  __shared__ float mp[L_], u1[L_], hv[L_], uu[L_], mv[L_], trp[L_], ktv[L_];
  __shared__ float Qv[L_], iQ[L_], sQ[L_], Ppv[L_], sPp[L_], m0v[L_];
  __shared__ float t1v[32], tPh[32], xbuf[32];
  __shared__ float ttv[16], ssv[16], rd16[16], y2v[16];

  float4 zr;  // carried z for (sp, lane_l*4 .. +3)

  // ---------------- init ----------------
  if (tid < L_) {
    float q = Qg[tid];  Qv[tid] = q;  iQ[tid] = 1.0f / q;  sQ[tid] = sqrtf(q);
    float p = Ppg[tid]; Ppv[tid] = p; sPp[tid] = sqrtf(p);
    m0v[tid] = m0g[tid];
  }
  __syncthreads();

  // ---------------- step 0 ----------------
  {
    if (tid < 512) { // stage K0^T
      const float* Ksrc = Kg + (size_t)b * T_ * L_ * R_;
      float4 v = *(const float4*)(Ksrc + tid * 4);
      int l = (tid * 4) >> 4, r = (tid * 4) & 15;
      KtT[r+0][l] = v.x; KtT[r+1][l] = v.y; KtT[r+2][l] = v.z; KtT[r+3][l] = v.w;
    }
    { // zp0 = sqrt(Pp)*w_p0
      int l = lane_l * 4;
      float4 w = *(const float4*)(wp0 + ((size_t)sp * B_ + b) * L_ + l);
      float4 p = *(const float4*)&sPp[l];
      *(float4*)&zp[sp][l] = make_float4(w.x*p.x, w.y*p.y, w.z*p.z, w.w*p.w);
    }
    if (tid < 512) { int s = tid >> 4, r = tid & 15;
      wfb[s][r] = wf0[((size_t)s * B_ + b) * R_ + r]; }
    __syncthreads();

    if (tid < 256) { // M16 = I + K0^T (Pp o K0)
      int r1 = tid >> 4, r2 = tid & 15;
      if (r1 <= r2) {
        float4 a4 = {0,0,0,0};
        for (int lc = 0; lc < 32; ++lc) {
          float4 a = *(const float4*)&KtT[r1][lc*4];
          float4 c = *(const float4*)&KtT[r2][lc*4];
          float4 p = *(const float4*)&Ppv[lc*4];
          a4.x += a.x*c.x*p.x; a4.y += a.y*c.y*p.y; a4.z += a.z*c.z*p.z; a4.w += a.w*c.w*p.w;
        }
        float acc = a4.x+a4.y+a4.z+a4.w + ((r1 == r2) ? 1.0f : 0.0f);
        C2m[r1][r2] = acc; C2m[r2][r1] = acc;
      }
      if (tid < 128) hv[tid] = m0v[tid] / Ppv[tid] + kg[(size_t)b * T_ * L_ + tid];
    } else if (tid < 512) {
      int q2 = tid - 256, s = q2 >> 3, r = (q2 & 7) * 2;
      float a0 = wfb[s][r], a1 = wfb[s][r+1];
      for (int lc = 0; lc < 32; ++lc) {
        float4 zz = *(const float4*)&zp[s][lc*4];
        float4 ka = *(const float4*)&KtT[r][lc*4];
        float4 kb = *(const float4*)&KtT[r+1][lc*4];
        a0 += dot4(zz, ka); a1 += dot4(zz, kb);
      }
      v1b[s][r] = a0; v1b[s][r+1] = a1;
    }
    __syncthreads();
    if (tid < 64) chol16_inv(tid, C2m, Gm, rd16);
    __syncthreads();
    if (tid < 512) { // tt partials ; y = G v1
      { int r = tid & 15, g = tid >> 4;
        float4 a = *(const float4*)&KtT[r][g*4];
        float4 p = *(const float4*)&Ppv[g*4];
        float4 h4 = *(const float4*)&hv[g*4];
        red[g][r] = a.x*p.x*h4.x + a.y*p.y*h4.y + a.z*p.z*h4.z + a.w*p.w*h4.w; }
      { int s = tid >> 4, r = tid & 15;
        float a = 0;
        #pragma unroll
        for (int j = 0; j < 16; ++j) a += Gm[r][j] * v1b[s][j];
        yb[s][r] = a; }
    }
    __syncthreads();
    if (tid < 512) { int s = tid >> 4, r = tid & 15; // x = G^T y
      float a = 0;
      #pragma unroll
      for (int j = 0; j < 16; ++j) a += Gm[j][r] * yb[s][j];
      xvb[s][r] = a; }
    if (tid < 64) { // ss = G^T G tt
      if (tid < 16) { float a = 0;
        #pragma unroll
        for (int g = 0; g < 32; ++g) a += red[g][tid];
        ttv[tid] = a; }
      wave_fence();
      if (tid < 16) { float a = 0;
        #pragma unroll
        for (int j = 0; j < 16; ++j) a += Gm[tid][j] * ttv[j];
        y2v[tid] = a; }
      wave_fence();
      if (tid < 16) { float a = 0;
        #pragma unroll
        for (int j = 0; j < 16; ++j) a += Gm[j][tid] * y2v[j];
        ssv[tid] = a; }
    }
    __syncthreads();
    if (tid < 128) {   // m = Pp*(h - K0 ss)
      float a = hv[tid];
      #pragma unroll
      for (int r = 0; r < 16; ++r) a -= KtT[r][tid] * ssv[r];
      mv[tid] = Ppv[tid] * a;
    }
    __syncthreads();
    { // z0 = m + zp - K0 x  -> registers + out
      int l0 = lane_l * 4;
      float4 acc = {0,0,0,0};
      #pragma unroll
      for (int r = 0; r < 16; ++r) {
        float xr = xvb[sp][r];
        float4 k = *(const float4*)&KtT[r][l0];
        acc.x += k.x*xr; acc.y += k.y*xr; acc.z += k.z*xr; acc.w += k.w*xr;
      }
      float4 m4 = *(const float4*)&mv[l0];
      float4 z4 = *(const float4*)&zp[sp][l0];
      zr.x = m4.x + z4.x - acc.x; zr.y = m4.y + z4.y - acc.y;
      zr.z = m4.z + z4.z - acc.z; zr.w = m4.w + z4.w - acc.w;
      *(float4*)(out + ((size_t)sp * B_ + b) * L_ + l0) = zr;
    }
    __syncthreads();
  }

  // ---------------- main loop ----------------
  for (int t = 1; t < T_; ++t) {
    // ---- stage-issue: global -> registers (latency hides under GEMMs) ----
    float4 kst; float wfst = 0.f, ktst = 0.f; float2 w1st; float4 w2st;
    {
      const float* w2src = wp2s + (((size_t)(t-1) * S_ + sp) * B_ + b) * L_ + lane_l * 4;
      w2st = *(const float4*)w2src;
      if (tid < 512) {
        const float* Ksrc = Kg + ((size_t)b * T_ + t) * L_ * R_;
        kst = *(const float4*)(Ksrc + tid * 4);
        wfst = wfs[(((size_t)(t-1) * S_ + (tid >> 4)) * B_ + b) * R_ + (tid & 15)];
        if (tid < 128) ktst = kg[((size_t)b * T_ + t) * L_ + tid];
      } else {
        int e = (tid - 512) * 2;
        w1st = *(const float2*)(wp1s + (((size_t)(t-1) * S_ + (e >> 5)) * B_ + b) * S_ + (e & 31));
      }
    }

    // ---- GEMM1 + GEMM2 fully in registers (z via shfl, A never leaves regs) ----
    {
      float acc1[8] = {0,0,0,0,0,0,0,0};
      #pragma unroll 2
      for (int kq = 0; kq < 32; ++kq) {
        float4 zk;
        zk.x = __shfl(zr.x, kq, 32); zk.y = __shfl(zr.y, kq, 32);
        zk.z = __shfl(zr.z, kq, 32); zk.w = __shfl(zr.w, kq, 32);
        const float* wbase = W1 + (size_t)kq * 1024 + lane_l * 8;
        float zv[4] = {zk.x, zk.y, zk.z, zk.w};
        #pragma unroll
        for (int q = 0; q < 4; ++q) {
          float4 wa = *(const float4*)(wbase + q * H_);
          float4 wb = *(const float4*)(wbase + q * H_ + 4);
          float zq = zv[q];
          acc1[0] += zq*wa.x; acc1[1] += zq*wa.y; acc1[2] += zq*wa.z; acc1[3] += zq*wa.w;
          acc1[4] += zq*wb.x; acc1[5] += zq*wb.y; acc1[6] += zq*wb.z; acc1[7] += zq*wb.w;
        }
      }
      float a8[8];
      #pragma unroll
      for (int j = 0; j < 8; ++j) a8[j] = tanhf(acc1[j]);
      float4 acc2 = {0,0,0,0};
      #pragma unroll 2
      for (int hq = 0; hq < 32; ++hq) {
        float av[8];
        av[0] = __shfl(a8[0], hq, 32); av[1] = __shfl(a8[1], hq, 32);
        av[2] = __shfl(a8[2], hq, 32); av[3] = __shfl(a8[3], hq, 32);
        av[4] = __shfl(a8[4], hq, 32); av[5] = __shfl(a8[5], hq, 32);
        av[6] = __shfl(a8[6], hq, 32); av[7] = __shfl(a8[7], hq, 32);
        const float* wbase = W2 + (size_t)hq * 1024 + lane_l * 4;
        #pragma unroll
        for (int j = 0; j < 8; ++j) {
          float4 w = *(const float4*)(wbase + j * L_);
          float aq = av[j];
          acc2.x += aq*w.x; acc2.y += aq*w.y; acc2.z += aq*w.z; acc2.w += aq*w.w;
        }
      }
      // m_theta = z + A@W2 -> Mc
      float4 mth = make_float4(zr.x+acc2.x, zr.y+acc2.y, zr.z+acc2.z, zr.w+acc2.w);
      *(float4*)&Mc[sp][lane_l*4] = mth;
    }

    // ---- stage-write: registers -> LDS ----
    if (tid < 512) {
      int l = (tid * 4) >> 4, r = (tid * 4) & 15;
      KtT[r+0][l] = kst.x; KtT[r+1][l] = kst.y; KtT[r+2][l] = kst.z; KtT[r+3][l] = kst.w;
      wfb[tid >> 4][tid & 15] = wfst;
      if (tid < 128) ktv[tid] = ktst;
    } else {
      int e = (tid - 512) * 2;
      w1b[e >> 5][e & 31] = w1st.x; w1b[e >> 5][(e & 31) + 1] = w1st.y;
    }
    __syncthreads();  // (A)

    if (tid < 128) { // ---- mean, u1 = mp/Q (4 chains) ----
      float a0=0, a1=0, a2=0, a3=0;
      #pragma unroll
      for (int s = 0; s < 32; s += 4) {
        a0 += Mc[s][tid]; a1 += Mc[s+1][tid]; a2 += Mc[s+2][tid]; a3 += Mc[s+3][tid];
      }
      float m = (a0+a1+a2+a3) * (1.0f / 32.0f);
      mp[tid] = m; u1[tid] = m * iQ[tid];
    }
    __syncthreads();  // (B)

    { // ---- center: Mc in place, Ab = McQ ----
      int l0 = lane_l * 4;
      float4 m4 = *(const float4*)&Mc[sp][l0];
      float4 p4 = *(const float4*)&mp[l0];
      float4 q4 = *(const float4*)&iQ[l0];
      const float cs = 0.17677669529663687f;
      float4 v4 = make_float4((m4.x-p4.x)*cs, (m4.y-p4.y)*cs, (m4.z-p4.z)*cs, (m4.w-p4.w)*cs);
      *(float4*)&Mc[sp][l0] = v4;
      *(float4*)&Ab[sp][l0] = make_float4(v4.x*q4.x, v4.y*q4.y, v4.z*q4.z, v4.w*q4.w);
    }
    __syncthreads();  // (C)

    { // ---- P5a: zp = Mc^T w1 + sqrt(Q)*w2 (shfl-broadcast, Mc rows read once/wave) ----
      float wrow = w1b[sp][lane_l];
      float4 az = {0,0,0,0};
      #pragma unroll 4
      for (int j = 0; j < 32; ++j) {
        float wj = __shfl(wrow, j, 32);
        float4 m4 = *(const float4*)&Mc[j][lane_l*4];
        az.x += wj*m4.x; az.y += wj*m4.y; az.z += wj*m4.z; az.w += wj*m4.w;
      }
      int l0 = lane_l * 4;
      float4 q4 = *(const float4*)&sQ[l0];
      *(float4*)&zp[sp][l0] = make_float4(az.x + q4.x*w2st.x, az.y + q4.y*w2st.y,
                                          az.z + q4.z*w2st.z, az.w + q4.w*w2st.w);
    }
    __syncthreads();  // (D)

    { // ---- P5b: C32 (sym) ; KM ; t1 partials ----
      { int s1 = tid >> 5, s2 = tid & 31;
        if (s1 <= s2) {
          float4 a4 = {0,0,0,0};
          for (int lc = 0; lc < 32; ++lc) {
            float4 a = *(const float4*)&Ab[s1][lc*4];
            float4 c = *(const float4*)&Mc[s2][lc*4];
            a4.x += a.x*c.x; a4.y += a.y*c.y; a4.z += a.z*c.z; a4.w += a.w*c.w;
          }
          float acc = a4.x+a4.y+a4.z+a4.w + ((s1 == s2) ? 1.0f : 0.0f);
          C32m[s1][s2] = acc; C32m[s2][s1] = acc;
        } }
      if (tid < 512) { int r = tid >> 5, s = tid & 31;   // KM[r][s]
        float4 a4 = {0,0,0,0};
        for (int lc = 0; lc < 32; ++lc) {
          float4 kk = *(const float4*)&KtT[r][lc*4];
          float4 mm = *(const float4*)&Mc[s][lc*4];
          a4.x += kk.x*mm.x; a4.y += kk.y*mm.y; a4.z += kk.z*mm.z; a4.w += kk.w*mm.w;
        }
        KMm[r][s] = a4.x+a4.y+a4.z+a4.w;
      } else { int g = tid - 512, s = g >> 4, seg = g & 15; // t1 partials
        float4 m1 = *(const float4*)&Mc[s][seg*8];
        float4 m2 = *(const float4*)&Mc[s][seg*8+4];
        float4 a1 = *(const float4*)&u1[seg*8];
        float4 a2 = *(const float4*)&u1[seg*8+4];
        red[s][seg] = dot4(m1, a1) + dot4(m2, a2);
      }
    }
    __syncthreads();  // (E)

    // ---- P6: KPK ; t1 reduce ; v1 ----
    if (tid < 256) {
      int r1 = tid >> 4, r2 = tid & 15;
      if (r1 <= r2) {
        float4 a4 = {0,0,0,0};
        #pragma unroll
        for (int sc2 = 0; sc2 < 8; ++sc2) {
          float4 a = *(const float4*)&KMm[r1][sc2*4];
          float4 c = *(const float4*)&KMm[r2][sc2*4];
          a4.x += a.x*c.x; a4.y += a.y*c.y; a4.z += a.z*c.z; a4.w += a.w*c.w;
        }
        for (int lc = 0; lc < 32; ++lc) {
          float4 a = *(const float4*)&KtT[r1][lc*4];
          float4 c = *(const float4*)&KtT[r2][lc*4];
          float4 q = *(const float4*)&Qv[lc*4];
          a4.x += a.x*c.x*q.x; a4.y += a.y*c.y*q.y; a4.z += a.z*c.z*q.z; a4.w += a.w*c.w*q.w;
        }
        float acc = a4.x+a4.y+a4.z+a4.w + ((r1 == r2) ? 1.0f : 0.0f);
        C2m[r1][r2] = acc; C2m[r2][r1] = acc;
      }
    } else if (tid < 288) {
      int s = tid - 256;
      float a = 0;
      #pragma unroll
      for (int g = 0; g < 16; ++g) a += red[s][g];
      t1v[s] = a;
    } else if (tid >= 512) {
      int g = tid - 512, s = g >> 4, r = g & 15;
      float4 a4 = {0,0,0,0};
      for (int lc = 0; lc < 32; ++lc) {
        float4 zz = *(const float4*)&zp[s][lc*4];
        float4 kk = *(const float4*)&KtT[r][lc*4];
        a4.x += zz.x*kk.x; a4.y += zz.y*kk.y; a4.z += zz.z*kk.z; a4.w += zz.w*kk.w;
      }
      v1b[s][r] = wfb[s][r] + a4.x+a4.y+a4.z+a4.w;
    }
    __syncthreads();  // (F)

    // ---- P7: wave0 chol32 ; wave1 chol16 ----
    if (tid < 64) chol32_fs(tid, C32m, t1v, xbuf);
    else if (tid < 128) chol16_inv(tid - 64, C2m, Gm, rd16);
    __syncthreads();  // (G)

    // ---- P8: wave0 = h->m chain ; waves1-8 = y,x,(zp-Kx) ----
    if (tid < 64) {
      const int ln = tid;
      const int l0 = ln, l1 = ln + 64;
      // hv = u1 + k - iQ * (sum_s Mc[s][l]*x[s])
      float p0=0,p1=0,p2=0,p3=0, q0=0,q1=0,q2=0,q3=0;
      #pragma unroll
      for (int s = 0; s < 32; s += 4) {
        float x0 = xbuf[s], x1 = xbuf[s+1], x2 = xbuf[s+2], x3 = xbuf[s+3];
        p0 += Mc[s][l0]*x0; p1 += Mc[s+1][l0]*x1; p2 += Mc[s+2][l0]*x2; p3 += Mc[s+3][l0]*x3;
        q0 += Mc[s][l1]*x0; q1 += Mc[s+1][l1]*x1; q2 += Mc[s+2][l1]*x2; q3 += Mc[s+3][l1]*x3;
      }
      hv[l0] = u1[l0] + ktv[l0] - iQ[l0] * (p0+p1+p2+p3);
      hv[l1] = u1[l1] + ktv[l1] - iQ[l1] * (q0+q1+q2+q3);
      wave_fence();
      { // tPh[s] = Mc[s] . hv
        int s = ln & 31, hb = (ln >> 5) * 64;
        float pa = 0, pb = 0;
        #pragma unroll
        for (int l = 0; l < 64; l += 8) {
          float4 m1 = *(const float4*)&Mc[s][hb+l];
          float4 h1 = *(const float4*)&hv[hb+l];
          float4 m2 = *(const float4*)&Mc[s][hb+l+4];
          float4 h2 = *(const float4*)&hv[hb+l+4];
          pa += dot4(m1, h1); pb += dot4(m2, h2);
        }
        float p = pa + pb;
        p += __shfl_xor(p, 32);
        if (ln < 32) tPh[s] = p;
      }
      wave_fence();
      // uu = Q*hv + sum_s Mc[s][l]*tPh[s]
      p0=0;p1=0;p2=0;p3=0;q0=0;q1=0;q2=0;q3=0;
      #pragma unroll
      for (int s = 0; s < 32; s += 4) {
        float x0 = tPh[s], x1 = tPh[s+1], x2 = tPh[s+2], x3 = tPh[s+3];
        p0 += Mc[s][l0]*x0; p1 += Mc[s+1][l0]*x1; p2 += Mc[s+2][l0]*x2; p3 += Mc[s+3][l0]*x3;
        q0 += Mc[s][l1]*x0; q1 += Mc[s+1][l1]*x1; q2 += Mc[s+2][l1]*x2; q3 += Mc[s+3][l1]*x3;
      }
      uu[l0] = Qv[l0]*hv[l0] + (p0+p1+p2+p3);
      uu[l1] = Qv[l1]*hv[l1] + (q0+q1+q2+q3);
      wave_fence();
      // tt[r] = KtT[r] . uu
      float ttr;
      { int r = ln & 15, qd = ln >> 4;
        float pa = 0, pb = 0;
        #pragma unroll
        for (int l = 0; l < 32; l += 8) {
          float4 k1 = *(const float4*)&KtT[r][qd*32+l];
          float4 u4 = *(const float4*)&uu[qd*32+l];
          float4 k2 = *(const float4*)&KtT[r][qd*32+l+4];
          float4 u5 = *(const float4*)&uu[qd*32+l+4];
          pa += dot4(k1, u4); pb += dot4(k2, u5);
        }
        float p = pa + pb;
        p += __shfl_xor(p, 16);
        p += __shfl_xor(p, 32);
        ttr = p;
      }
      // ss = G^T (G tt)
      { int r = ln & 15;
        float y2 = 0;
        #pragma unroll
        for (int j = 0; j < 16; ++j) y2 += Gm[r][j] * __shfl(ttr, j);
        float ssr = 0;
        #pragma unroll
        for (int j = 0; j < 16; ++j) ssr += Gm[j][r] * __shfl(y2, j);
        if (ln < 16) ssv[r] = ssr;
      }
      wave_fence();
      // trp = K ss
      { float a0 = 0, a1 = 0;
        #pragma unroll
        for (int r = 0; r < 16; ++r) {
          float sr = ssv[r];
          a0 += KtT[r][l0] * sr; a1 += KtT[r][l1] * sr;
        }
        trp[l0] = a0; trp[l1] = a1; }
      wave_fence();
      { // tP2[s] = Mc[s] . trp
        int s = ln & 31, hb = (ln >> 5) * 64;
        float pa = 0, pb = 0;
        #pragma unroll
        for (int l = 0; l < 64; l += 8) {
          float4 m1 = *(const float4*)&Mc[s][hb+l];
          float4 h1 = *(const float4*)&trp[hb+l];
          float4 m2 = *(const float4*)&Mc[s][hb+l+4];
          float4 h2 = *(const float4*)&trp[hb+l+4];
          pa += dot4(m1, h1); pb += dot4(m2, h2);
        }
        float p = pa + pb;
        p += __shfl_xor(p, 32);
        if (ln < 32) tPh[s] = p;
      }
      wave_fence();
      // mv = uu - Q*trp - sum_s Mc[s][l]*tP2[s]
      p0=0;p1=0;p2=0;p3=0;q0=0;q1=0;q2=0;q3=0;
      #pragma unroll
      for (int s = 0; s < 32; s += 4) {
        float x0 = tPh[s], x1 = tPh[s+1], x2 = tPh[s+2], x3 = tPh[s+3];
        p0 += Mc[s][l0]*x0; p1 += Mc[s+1][l0]*x1; p2 += Mc[s+2][l0]*x2; p3 += Mc[s+3][l0]*x3;
        q0 += Mc[s][l1]*x0; q1 += Mc[s+1][l1]*x1; q2 += Mc[s+2][l1]*x2; q3 += Mc[s+3][l1]*x3;
      }
      mv[l0] = uu[l0] - Qv[l0]*trp[l0] - (p0+p1+p2+p3);
      mv[l1] = uu[l1] - Qv[l1]*trp[l1] - (q0+q1+q2+q3);
    } else if (tid < 576) {
      int g = tid - 64;
      int s = g >> 4, r = g & 15;
      int sb = g & 48;
      float yv = 0;
      #pragma unroll
      for (int j = 0; j < 16; ++j) yv += Gm[r][j] * v1b[s][j];
      float xr_ = 0;
      #pragma unroll
      for (int j = 0; j < 16; ++j) xr_ += Gm[j][r] * __shfl(yv, sb + j);
      float xl[16];
      #pragma unroll
      for (int j = 0; j < 16; ++j) xl[j] = __shfl(xr_, sb + j);
      int lb = r * 8;
      float4 ac1 = {0,0,0,0}, ac2 = {0,0,0,0};
      #pragma unroll
      for (int r2 = 0; r2 < 16; ++r2) {
        float xr = xl[r2];
        float4 k1 = *(const float4*)&KtT[r2][lb];
        float4 k2 = *(const float4*)&KtT[r2][lb+4];
        ac1.x += xr*k1.x; ac1.y += xr*k1.y; ac1.z += xr*k1.z; ac1.w += xr*k1.w;
        ac2.x += xr*k2.x; ac2.y += xr*k2.y; ac2.z += xr*k2.z; ac2.w += xr*k2.w;
      }
      float4 z1 = *(const float4*)&zp[s][lb];
      float4 z2 = *(const float4*)&zp[s][lb+4];
      z1.x -= ac1.x; z1.y -= ac1.y; z1.z -= ac1.z; z1.w -= ac1.w;
      z2.x -= ac2.x; z2.y -= ac2.y; z2.z -= ac2.z; z2.w -= ac2.w;
      *(float4*)&zp[s][lb] = z1; *(float4*)&zp[s][lb+4] = z2;
    }
    __syncthreads();  // (H)

    { // ---- store: z = mv + (zp - Kx), keep in regs ----
      int l0 = lane_l * 4;
      float4 z4 = *(const float4*)&zp[sp][l0];
      float4 m4 = *(const float4*)&mv[l0];
      zr.x = z4.x + m4.x; zr.y = z4.y + m4.y; zr.z = z4.z + m4.z; zr.w = z4.w + m4.w;
      *(float4*)(out + (((size_t)t * S_ + sp) * B_ + b) * L_ + l0) = zr;
    }
    // no barrier needed: next writes to any buffer are >=2 barriers away
  }
}

extern "C" void kernel_launch(void* const* d_in, const int* in_sizes, int n_in,
                              void* d_out, int out_size, void* d_ws, size_t ws_size,
                              hipStream_t stream) {
  const float* kg  = (const float*)d_in[0];
  const float* Kg  = (const float*)d_in[1];
  const float* m0  = (const float*)d_in[2];
  const float* Pp  = (const float*)d_in[3];
  const float* Qd  = (const float*)d_in[4];
  const float* W1  = (const float*)d_in[5];
  const float* W2  = (const float*)d_in[6];
  const float* wp0 = (const float*)d_in[7];
  const float* wf0 = (const float*)d_in[8];
  const float* wp1 = (const float*)d_in[9];
  const float* wp2 = (const float*)d_in[10];
  const float* wfs = (const float*)d_in[11];
  float* outp = (float*)d_out;
  (void)d_ws; (void)ws_size;

  filter_kernel<<<B_, 1024, 0, stream>>>(kg, Kg, m0, Pp, Qd, wp0, wf0,
                                         wp1, wp2, wfs, W1, W2, outp);
}